// Round 4
// baseline (670.537 us; speedup 1.0000x reference)
//
#include <hip/hip_runtime.h>

typedef unsigned short ushort_t;
typedef __attribute__((ext_vector_type(8))) short short8;
typedef __attribute__((ext_vector_type(4))) float floatx4;

// ---------- helpers ----------
__device__ __forceinline__ ushort_t f2bf(float f) {
    unsigned u = __float_as_uint(f);
    return (ushort_t)((u + 0x7fffu + ((u >> 16) & 1u)) >> 16);
}
__device__ __forceinline__ void gll16(const void* g, void* l) {
    __builtin_amdgcn_global_load_lds(
        (const __attribute__((address_space(1))) unsigned int*)g,
        (__attribute__((address_space(3))) unsigned int*)l, 16, 0, 0);
}

// ---------- prep: cast x -> bf16 (y==0) ; transpose+cast wq/wk (y==1) ----------
__global__ void prep_kernel(const float* __restrict__ x, ushort_t* __restrict__ xb,
                            const float* __restrict__ wq, const float* __restrict__ wk,
                            ushort_t* __restrict__ wqT, ushort_t* __restrict__ wkT) {
    if (blockIdx.y == 0) {
        size_t i = ((size_t)blockIdx.x * 256 + threadIdx.x) * 8;
        float4 v0 = *(const float4*)(x + i);
        float4 v1 = *(const float4*)(x + i + 4);
        uint4 o;
        o.x = (unsigned)f2bf(v0.x) | ((unsigned)f2bf(v0.y) << 16);
        o.y = (unsigned)f2bf(v0.z) | ((unsigned)f2bf(v0.w) << 16);
        o.z = (unsigned)f2bf(v1.x) | ((unsigned)f2bf(v1.y) << 16);
        o.w = (unsigned)f2bf(v1.z) | ((unsigned)f2bf(v1.w) << 16);
        *(uint4*)(xb + i) = o;
    } else {
        int idx = blockIdx.x * 256 + threadIdx.x;          // 0..2M
        const float* src = (idx >> 20) ? wk : wq;
        ushort_t* dst = (idx >> 20) ? wkT : wqT;
        int id2 = idx & 1048575;
        int nrow = id2 >> 10, k = id2 & 1023;
        dst[id2] = f2bf(src[k * 1024 + nrow]);
    }
}

// ---------- MFMA bf16 GEMM (m97-style global_load_lds staging) ----------
__global__ __launch_bounds__(256) void gemm_qk_kernel(
    const ushort_t* __restrict__ xb, const ushort_t* __restrict__ wqT, const ushort_t* __restrict__ wkT,
    const float* __restrict__ bq, const float* __restrict__ bk,
    ushort_t* __restrict__ Qb, ushort_t* __restrict__ Kb)
{
    const int bm = blockIdx.x;          // 128 M-tiles of 128
    const int bn = blockIdx.y;          // 8 N-tiles of 128
    const int mat = blockIdx.z;         // 0=Q, 1=K
    const ushort_t* W = mat ? wkT : wqT;
    const float* bias = mat ? bk : bq;
    ushort_t* Out = mat ? Kb : Qb;
    const float postscale = mat ? 1.0f : 0.08838834764831845f;

    __shared__ ushort_t a_lds[128 * 32];
    __shared__ ushort_t b_lds[128 * 32];

    const int tid = threadIdx.x;
    const int lane = tid & 63;
    const int wave = tid >> 6;
    const int wr = wave >> 1, wc = wave & 1;
    const int l16 = lane & 15, quad = lane >> 4;

    floatx4 acc[4][4];
    const floatx4 zero4 = {0.f, 0.f, 0.f, 0.f};
#pragma unroll
    for (int i = 0; i < 4; ++i)
#pragma unroll
        for (int j = 0; j < 4; ++j) acc[i][j] = zero4;

    const int srow = wave * 32 + (lane >> 2);
    const int skof = (lane & 3) * 8;
    const ushort_t* gA = xb + (size_t)(bm * 128 + srow) * 1024 + skof;
    const ushort_t* gB = W + (size_t)(bn * 128 + srow) * 1024 + skof;
    ushort_t* lA = &a_lds[wave * 1024];
    ushort_t* lB = &b_lds[wave * 1024];

    for (int kt = 0; kt < 32; ++kt) {
        const int k0 = kt * 32;
        __syncthreads();
        gll16(gA + k0, lA);
        gll16(gA + k0 + 16 * 1024, lA + 512);
        gll16(gB + k0, lB);
        gll16(gB + k0 + 16 * 1024, lB + 512);
        __syncthreads();
        short8 afr[4], bfr[4];
#pragma unroll
        for (int mi = 0; mi < 4; ++mi)
            afr[mi] = *(const short8*)&a_lds[(wr * 64 + mi * 16 + l16) * 32 + quad * 8];
#pragma unroll
        for (int ni = 0; ni < 4; ++ni)
            bfr[ni] = *(const short8*)&b_lds[(wc * 64 + ni * 16 + l16) * 32 + quad * 8];
#pragma unroll
        for (int mi = 0; mi < 4; ++mi)
#pragma unroll
            for (int ni = 0; ni < 4; ++ni)
                acc[mi][ni] = __builtin_amdgcn_mfma_f32_16x16x32_bf16(afr[mi], bfr[ni], acc[mi][ni], 0, 0, 0);
    }
#pragma unroll
    for (int mi = 0; mi < 4; ++mi) {
#pragma unroll
        for (int ni = 0; ni < 4; ++ni) {
            const int gcol = bn * 128 + wc * 64 + ni * 16 + l16;
            const int h = gcol >> 7, d = gcol & 127;
#pragma unroll
            for (int r = 0; r < 4; ++r) {
                const int grow = bm * 128 + wr * 64 + mi * 16 + quad * 4 + r;
                const int b = grow >> 10, s = grow & 1023;
                Out[(((size_t)(b * 8 + h)) * 1024 + s) * 128 + d] =
                    f2bf((acc[mi][ni][r] + bias[gcol]) * postscale);
            }
        }
    }
}

// ---------- attention column sums via MFMA, double-buffered DMA staging ----------
// K-tile staged with global_load_lds: LDS dest is lane-contiguous (HW constraint),
// the XOR swizzle is applied to the per-lane GLOBAL source address instead.
__global__ __launch_bounds__(256) void attn_mfma_kernel(
    const ushort_t* __restrict__ Qb,   // [bh][1024][128] bf16 (scaled)
    const ushort_t* __restrict__ Kb,   // [bh][1024][128] bf16
    float* __restrict__ wout)          // [bh][1024], zero-init
{
    const int bh = blockIdx.x;         // 128
    const int qt = blockIdx.y;         // 8 q-tiles of 128 rows
    __shared__ ushort_t ks[2][128 * 128]; // 2 x 32 KB, XOR-swizzled 16B granules

    const int tid = threadIdx.x;
    const int wave = tid >> 6, lane = tid & 63;
    const int l16 = lane & 15, quad = lane >> 4;

    const ushort_t* Ksrc = Kb + (size_t)bh * 1024 * 128;

    // inverse-swizzled per-lane source offsets: call c covers LDS rows
    // wave*32+c*4+(lane>>4); content col-group g = (lane&15) ^ (row&15)
    int srcoff[8];
#pragma unroll
    for (int c = 0; c < 8; ++c) {
        int r = wave * 32 + c * 4 + (lane >> 4);
        int g = (lane & 15) ^ (r & 15);
        srcoff[c] = r * 128 + g * 8;
    }

    auto issue = [&](int buf, int kt) {
        const ushort_t* src = Ksrc + (size_t)kt * 16384;
#pragma unroll
        for (int c = 0; c < 8; ++c)
            gll16(src + srcoff[c], &ks[buf][(wave * 8 + c) * 512]);
    };

    // Q fragments, kept in registers for both passes
    short8 aq[2][4];
    {
        const ushort_t* qsrc = Qb + ((size_t)bh * 1024 + qt * 128 + wave * 32) * 128;
#pragma unroll
        for (int mi = 0; mi < 2; ++mi)
#pragma unroll
            for (int ksp = 0; ksp < 4; ++ksp)
                aq[mi][ksp] = *(const short8*)(qsrc + (size_t)(mi * 16 + l16) * 128 + ksp * 32 + quad * 8);
    }

    const floatx4 zero4 = {0.f, 0.f, 0.f, 0.f};
    float lsum[2][4];
#pragma unroll
    for (int mi = 0; mi < 2; ++mi)
#pragma unroll
        for (int r = 0; r < 4; ++r) lsum[mi][r] = 0.f;

    issue(0, 0);

    // ---- pass 1: row sums of exp(s) ----
    for (int kt = 0; kt < 8; ++kt) {
        __syncthreads();                       // drains buf[kt&1] loads
        if (kt < 7) issue((kt + 1) & 1, kt + 1);
        const ushort_t* kbuf = ks[kt & 1];
        floatx4 acc[2][8];
#pragma unroll
        for (int mi = 0; mi < 2; ++mi)
#pragma unroll
            for (int ni = 0; ni < 8; ++ni) acc[mi][ni] = zero4;
#pragma unroll
        for (int ksp = 0; ksp < 4; ++ksp) {
            short8 bk[8];
#pragma unroll
            for (int ni = 0; ni < 8; ++ni) {
                int n = ni * 16 + l16;
                int gs = (ksp * 4 + quad) ^ (n & 15);
                bk[ni] = *(const short8*)&kbuf[n * 128 + gs * 8];
            }
#pragma unroll
            for (int mi = 0; mi < 2; ++mi)
#pragma unroll
                for (int ni = 0; ni < 8; ++ni)
                    acc[mi][ni] = __builtin_amdgcn_mfma_f32_16x16x32_bf16(aq[mi][ksp], bk[ni], acc[mi][ni], 0, 0, 0);
        }
#pragma unroll
        for (int mi = 0; mi < 2; ++mi)
#pragma unroll
            for (int r = 0; r < 4; ++r) {
                float s = 0.f;
#pragma unroll
                for (int ni = 0; ni < 8; ++ni) s += __expf(acc[mi][ni][r]);
                lsum[mi][r] += s;
            }
    }

    issue(0, 0);    // prefetch pass-2 tile 0 (buf0's last reader was kt=6, done)

    float invl[2][4];
#pragma unroll
    for (int mi = 0; mi < 2; ++mi)
#pragma unroll
        for (int r = 0; r < 4; ++r) {
            float s = lsum[mi][r];
#pragma unroll
            for (int off = 1; off < 16; off <<= 1) s += __shfl_xor(s, off, 16);
            invl[mi][r] = 1.f / s;
        }

    // ---- pass 2: column sums of exp(s)/l ----
    for (int kt = 0; kt < 8; ++kt) {
        __syncthreads();
        if (kt < 7) issue((kt + 1) & 1, kt + 1);
        const ushort_t* kbuf = ks[kt & 1];
        floatx4 acc[2][8];
#pragma unroll
        for (int mi = 0; mi < 2; ++mi)
#pragma unroll
            for (int ni = 0; ni < 8; ++ni) acc[mi][ni] = zero4;
#pragma unroll
        for (int ksp = 0; ksp < 4; ++ksp) {
            short8 bk[8];
#pragma unroll
            for (int ni = 0; ni < 8; ++ni) {
                int n = ni * 16 + l16;
                int gs = (ksp * 4 + quad) ^ (n & 15);
                bk[ni] = *(const short8*)&kbuf[n * 128 + gs * 8];
            }
#pragma unroll
            for (int mi = 0; mi < 2; ++mi)
#pragma unroll
                for (int ni = 0; ni < 8; ++ni)
                    acc[mi][ni] = __builtin_amdgcn_mfma_f32_16x16x32_bf16(aq[mi][ksp], bk[ni], acc[mi][ni], 0, 0, 0);
        }
#pragma unroll
        for (int ni = 0; ni < 8; ++ni) {
            float s = 0.f;
#pragma unroll
            for (int mi = 0; mi < 2; ++mi)
#pragma unroll
                for (int r = 0; r < 4; ++r)
                    s += __expf(acc[mi][ni][r]) * invl[mi][r];
            s += __shfl_xor(s, 16, 64);
            s += __shfl_xor(s, 32, 64);
            if (quad == 0) atomicAdd(&wout[bh * 1024 + kt * 128 + ni * 16 + l16], s);
        }
    }
}

// ---------- u[b,h,:] = sum_k w[b,h,k] * x[b,k,:] ----------
__global__ __launch_bounds__(256) void u_kernel(const float* __restrict__ x,
                                                const float* __restrict__ w,
                                                float* __restrict__ u)
{
    const int b = blockIdx.x, kc = blockIdx.y;
    const int c4 = threadIdx.x;
    const float4* X4 = (const float4*)(x + ((size_t)(b * 1024 + kc * 64)) * 1024);
    float4 acc[8];
#pragma unroll
    for (int h = 0; h < 8; ++h) acc[h] = make_float4(0.f, 0.f, 0.f, 0.f);
    const float* wb = w + b * 8 * 1024 + kc * 64;
    for (int k = 0; k < 64; ++k) {
        float4 xv = X4[(size_t)k * 256 + c4];
#pragma unroll
        for (int h = 0; h < 8; ++h) {
            float ww = wb[h * 1024 + k];
            acc[h].x = fmaf(ww, xv.x, acc[h].x);
            acc[h].y = fmaf(ww, xv.y, acc[h].y);
            acc[h].z = fmaf(ww, xv.z, acc[h].z);
            acc[h].w = fmaf(ww, xv.w, acc[h].w);
        }
    }
#pragma unroll
    for (int h = 0; h < 8; ++h) {
        float* dst = u + ((size_t)(b * 8 + h)) * 1024 + c4 * 4;
        atomicAdd(dst + 0, acc[h].x);
        atomicAdd(dst + 1, acc[h].y);
        atomicAdd(dst + 2, acc[h].z);
        atomicAdd(dst + 3, acc[h].w);
    }
}

// ---------- small GEMM with split-K ----------
__global__ __launch_bounds__(256) void sgemm_kernel(
    const float* __restrict__ A, int lda, long sAz,
    const float* __restrict__ Bm, int ldb, long sBz,
    const float* __restrict__ bias, long sBiasz,
    float* __restrict__ C, int ldc, long sCz,
    int M, int N, int K, float alpha, int nks)
{
    const int z = blockIdx.z;
    const int ks = blockIdx.x % nks;
    const int mt = blockIdx.x / nks;
    const int Kc = K / nks;
    A += (size_t)z * sAz;
    Bm += (size_t)z * sBz;
    C += (size_t)z * sCz;
    const float* bptr = bias ? bias + (size_t)z * sBiasz : nullptr;
    __shared__ float As[64 * 36];
    __shared__ float Bs[32 * 68];
    const int tid = threadIdx.x;
    const int row0 = mt * 64, col0 = blockIdx.y * 64;
    const int ty = tid >> 4, tx = tid & 15;
    float acc[4][4] = {};
    const int aflat = tid * 8;
    const int ar = aflat >> 5, ac = aflat & 31;
    const int br = aflat >> 6, bc = aflat & 63;
    for (int k0 = ks * Kc; k0 < (ks + 1) * Kc; k0 += 32) {
        __syncthreads();
        float4 va0 = make_float4(0.f, 0.f, 0.f, 0.f), va1 = va0;
        if (row0 + ar < M) {
            const float* src = A + (size_t)(row0 + ar) * lda + k0 + ac;
            va0 = *(const float4*)src;
            va1 = *(const float4*)(src + 4);
        }
        *(float4*)&As[ar * 36 + ac] = va0;
        *(float4*)&As[ar * 36 + ac + 4] = va1;
        {
            const float* srcb = Bm + (size_t)(k0 + br) * ldb + col0 + bc;
            *(float4*)&Bs[br * 68 + bc] = *(const float4*)srcb;
            *(float4*)&Bs[br * 68 + bc + 4] = *(const float4*)(srcb + 4);
        }
        __syncthreads();
#pragma unroll
        for (int kk = 0; kk < 32; ++kk) {
            float a0 = As[(ty * 4 + 0) * 36 + kk];
            float a1 = As[(ty * 4 + 1) * 36 + kk];
            float a2 = As[(ty * 4 + 2) * 36 + kk];
            float a3 = As[(ty * 4 + 3) * 36 + kk];
            float b0 = Bs[kk * 68 + tx * 4 + 0];
            float b1 = Bs[kk * 68 + tx * 4 + 1];
            float b2 = Bs[kk * 68 + tx * 4 + 2];
            float b3 = Bs[kk * 68 + tx * 4 + 3];
            acc[0][0] = fmaf(a0, b0, acc[0][0]); acc[0][1] = fmaf(a0, b1, acc[0][1]);
            acc[0][2] = fmaf(a0, b2, acc[0][2]); acc[0][3] = fmaf(a0, b3, acc[0][3]);
            acc[1][0] = fmaf(a1, b0, acc[1][0]); acc[1][1] = fmaf(a1, b1, acc[1][1]);
            acc[1][2] = fmaf(a1, b2, acc[1][2]); acc[1][3] = fmaf(a1, b3, acc[1][3]);
            acc[2][0] = fmaf(a2, b0, acc[2][0]); acc[2][1] = fmaf(a2, b1, acc[2][1]);
            acc[2][2] = fmaf(a2, b2, acc[2][2]); acc[2][3] = fmaf(a2, b3, acc[2][3]);
            acc[3][0] = fmaf(a3, b0, acc[3][0]); acc[3][1] = fmaf(a3, b1, acc[3][1]);
            acc[3][2] = fmaf(a3, b2, acc[3][2]); acc[3][3] = fmaf(a3, b3, acc[3][3]);
        }
    }
#pragma unroll
    for (int i = 0; i < 4; ++i) {
        int r = row0 + ty * 4 + i;
        if (r >= M) continue;
#pragma unroll
        for (int j = 0; j < 4; ++j) {
            int c = col0 + tx * 4 + j;
            float v = alpha * acc[i][j] + ((bptr && ks == 0) ? bptr[c] : 0.f);
            if (nks > 1) atomicAdd(&C[(size_t)r * ldc + c], v);
            else C[(size_t)r * ldc + c] = v;
        }
    }
}

// ---------- fused gate: h1=tanh -> logits -> softmax -> DR = rw @ emb ----------
__global__ __launch_bounds__(256) void gate_kernel(
    const float* __restrict__ Ge, const float* __restrict__ Ee, const float* __restrict__ rg_b1,
    const float* __restrict__ rg_w2, const float* __restrict__ rg_b2,
    const float* __restrict__ emb, float* __restrict__ DR)
{
    const int row = blockIdx.x;       // 1024 = b*64+n
    const int b = row >> 6, n = row & 63;
    __shared__ float h[1024];
    __shared__ float red[256];
    __shared__ float rw[64];
    const int tid = threadIdx.x;
    for (int c = tid; c < 1024; c += 256)
        h[c] = tanhf(Ge[b * 1024 + c] + Ee[n * 1024 + c] + rg_b1[c]);
    __syncthreads();
    const int j = tid & 63, ch = tid >> 6;
    float part = 0.f;
    const float* w2p = rg_w2 + (size_t)(ch * 256) * 64 + j;
    for (int c = 0; c < 256; ++c)
        part = fmaf(h[ch * 256 + c], w2p[c * 64], part);
    red[tid] = part;
    __syncthreads();
    if (tid < 64) {
        float lg = red[tid] + red[tid + 64] + red[tid + 128] + red[tid + 192] + rg_b2[j];
        float m = lg;
#pragma unroll
        for (int off = 1; off < 64; off <<= 1) m = fmaxf(m, __shfl_xor(m, off, 64));
        float e = __expf(lg - m);
        float s = e;
#pragma unroll
        for (int off = 1; off < 64; off <<= 1) s += __shfl_xor(s, off, 64);
        rw[tid] = e / s;
    }
    __syncthreads();
    float4 acc = make_float4(0.f, 0.f, 0.f, 0.f);
    const float4* E4 = (const float4*)emb;
    for (int nn = 0; nn < 64; ++nn) {
        float wv = rw[nn];
        float4 ev = E4[nn * 256 + tid];
        acc.x = fmaf(wv, ev.x, acc.x);
        acc.y = fmaf(wv, ev.y, acc.y);
        acc.z = fmaf(wv, ev.z, acc.z);
        acc.w = fmaf(wv, ev.w, acc.w);
    }
    *(float4*)&DR[(size_t)row * 1024 + tid * 4] = acc;
}

// ---------- per-device heads: all 16 batch rows per block, W1 read once ----------
__global__ __launch_bounds__(256) void heads_kernel(
    const float* __restrict__ g, const float* __restrict__ DR,
    const float* __restrict__ rw1, const float* __restrict__ rb1,
    const float* __restrict__ rw2, const float* __restrict__ rb2,
    const float* __restrict__ cw1, const float* __restrict__ cb1,
    const float* __restrict__ cw2, const float* __restrict__ cb2,
    float* __restrict__ out)
{
    const int n = blockIdx.x, task = blockIdx.y;   // 64 x 2
    __shared__ float comb[16 * 1024];              // 64 KB
    __shared__ float hid[16 * 129];
    for (int i = threadIdx.x; i < 16 * 1024; i += 256) {
        int b = i >> 10, c = i & 1023;
        comb[i] = g[b * 1024 + c] + DR[((size_t)(b * 64 + n)) * 1024 + c];
    }
    __syncthreads();
    const float* W1 = (task ? cw1 : rw1) + (size_t)n * 1024 * 128;
    const int j = threadIdx.x & 127, sub = threadIdx.x >> 7;   // 2 subs x 8 b
    float a[8] = {};
    for (int c = 0; c < 1024; ++c) {
        float wv1 = W1[c * 128 + j];
        const float* cb = &comb[(sub * 8) * 1024 + c];
#pragma unroll
        for (int bb = 0; bb < 8; ++bb) a[bb] = fmaf(cb[bb * 1024], wv1, a[bb]);
    }
    float bj = (task ? cb1 : rb1)[n * 128 + j];
#pragma unroll
    for (int bb = 0; bb < 8; ++bb)
        hid[(sub * 8 + bb) * 129 + j] = fmaxf(a[bb] + bj, 0.f);
    __syncthreads();
    if (threadIdx.x < 16) {
        int b = threadIdx.x;
        const float* W2 = (task ? cw2 : rw2) + n * 128;
        float s = (task ? cb2 : rb2)[n];
        for (int jj = 0; jj < 128; ++jj) s = fmaf(hid[b * 129 + jj], W2[jj], s);
        float r = task ? (1.f / (1.f + __expf(-s)))
                       : (fmaxf(s, 0.f) + log1pf(__expf(-fabsf(s))));
        out[task * 1024 + b * 64 + n] = r;
    }
}

// ---------- launch ----------
extern "C" void kernel_launch(void* const* d_in, const int* in_sizes, int n_in,
                              void* d_out, int out_size, void* d_ws, size_t ws_size,
                              hipStream_t stream)
{
    const float* x      = (const float*)d_in[0];
    const float* wq     = (const float*)d_in[1];
    const float* bq     = (const float*)d_in[2];
    const float* wk     = (const float*)d_in[3];
    const float* bk     = (const float*)d_in[4];
    const float* wv     = (const float*)d_in[5];
    const float* bv     = (const float*)d_in[6];
    const float* wo     = (const float*)d_in[7];
    const float* bo     = (const float*)d_in[8];
    const float* emb    = (const float*)d_in[9];
    const float* rg_w1  = (const float*)d_in[10];
    const float* rg_b1  = (const float*)d_in[11];
    const float* rg_w2  = (const float*)d_in[12];
    const float* rg_b2  = (const float*)d_in[13];
    const float* reg_w1 = (const float*)d_in[14];
    const float* reg_b1 = (const float*)d_in[15];
    const float* reg_w2 = (const float*)d_in[16];
    const float* reg_b2 = (const float*)d_in[17];
    const float* cls_w1 = (const float*)d_in[18];
    const float* cls_b1 = (const float*)d_in[19];
    const float* cls_w2 = (const float*)d_in[20];
    const float* cls_b2 = (const float*)d_in[21];

    char* ws = (char*)d_ws;
    size_t off = 0;
    auto alloc = [&](size_t bytes) { size_t cur = off; off += (bytes + 255) & ~(size_t)255; return cur; };

    ushort_t* xb  = (ushort_t*)(ws + alloc((size_t)16777216 * 2));
    ushort_t* wqT = (ushort_t*)(ws + alloc((size_t)1048576 * 2));
    ushort_t* wkT = (ushort_t*)(ws + alloc((size_t)1048576 * 2));
    ushort_t* Qb  = (ushort_t*)(ws + alloc((size_t)16777216 * 2));
    ushort_t* Kb  = (ushort_t*)(ws + alloc((size_t)16777216 * 2));
    size_t zero_beg = off;
    float* wcol = (float*)(ws + alloc((size_t)131072 * 4));
    float* u    = (float*)(ws + alloc((size_t)131072 * 4));
    float* cm   = (float*)(ws + alloc((size_t)16384 * 4));
    float* gbuf = (float*)(ws + alloc((size_t)16384 * 4));
    float* Ge   = (float*)(ws + alloc((size_t)16384 * 4));
    float* Ee   = (float*)(ws + alloc((size_t)65536 * 4));
    size_t zero_end = off;
    float* DR   = (float*)(ws + alloc((size_t)1048576 * 4));

    hipMemsetAsync(ws + zero_beg, 0, zero_end - zero_beg, stream);

    prep_kernel<<<dim3(8192, 2), 256, 0, stream>>>(x, xb, wq, wk, wqT, wkT);
    gemm_qk_kernel<<<dim3(128, 8, 2), 256, 0, stream>>>(xb, wqT, wkT, bq, bk, Qb, Kb);
    attn_mfma_kernel<<<dim3(128, 8), 256, 0, stream>>>(Qb, Kb, wcol);
    u_kernel<<<dim3(16, 16), 256, 0, stream>>>(x, wcol, u);
    sgemm_kernel<<<dim3(4, 2, 8), 256, 0, stream>>>(u, 8192, 1024, wv, 1024, 128, bv, 128,
                                                    cm, 1024, 128, 16, 128, 1024, 1.f / 1024.f, 4);
    sgemm_kernel<<<dim3(8, 16, 1), 256, 0, stream>>>(cm, 1024, 0, wo, 1024, 0, bo, 0,
                                                     gbuf, 1024, 0, 16, 1024, 1024, 1.f, 8);
    sgemm_kernel<<<dim3(8, 16, 1), 256, 0, stream>>>(gbuf, 1024, 0, rg_w1, 1024, 0, nullptr, 0,
                                                     Ge, 1024, 0, 16, 1024, 1024, 1.f, 8);
    sgemm_kernel<<<dim3(8, 16, 1), 256, 0, stream>>>(emb, 1024, 0, rg_w1 + (size_t)1048576, 1024, 0, nullptr, 0,
                                                     Ee, 1024, 0, 64, 1024, 1024, 1.f, 8);
    gate_kernel<<<1024, 256, 0, stream>>>(Ge, Ee, rg_b1, rg_w2, rg_b2, emb, DR);
    heads_kernel<<<dim3(64, 2), 256, 0, stream>>>(gbuf, DR, reg_w1, reg_b1, reg_w2, reg_b2,
                                                  cls_w1, cls_b1, cls_w2, cls_b2, (float*)d_out);
    (void)in_sizes; (void)n_in; (void)out_size; (void)ws_size;
}

// Round 5
// 562.447 us; speedup vs baseline: 1.1922x; 1.1922x over previous
//
#include <hip/hip_runtime.h>

typedef unsigned short ushort_t;
typedef __attribute__((ext_vector_type(8))) short short8;
typedef __attribute__((ext_vector_type(4))) float floatx4;

// ---------- helpers ----------
__device__ __forceinline__ ushort_t f2bf(float f) {
    unsigned u = __float_as_uint(f);
    return (ushort_t)((u + 0x7fffu + ((u >> 16) & 1u)) >> 16);
}
__device__ __forceinline__ void gll16(const void* g, void* l) {
    __builtin_amdgcn_global_load_lds(
        (const __attribute__((address_space(1))) unsigned int*)g,
        (__attribute__((address_space(3))) unsigned int*)l, 16, 0, 0);
}

// ---------- prep: cast x -> bf16 (y==0) ; transpose+cast wq/wk (y==1) ----------
__global__ void prep_kernel(const float* __restrict__ x, ushort_t* __restrict__ xb,
                            const float* __restrict__ wq, const float* __restrict__ wk,
                            ushort_t* __restrict__ wqT, ushort_t* __restrict__ wkT) {
    if (blockIdx.y == 0) {
        size_t i = ((size_t)blockIdx.x * 256 + threadIdx.x) * 8;
        float4 v0 = *(const float4*)(x + i);
        float4 v1 = *(const float4*)(x + i + 4);
        uint4 o;
        o.x = (unsigned)f2bf(v0.x) | ((unsigned)f2bf(v0.y) << 16);
        o.y = (unsigned)f2bf(v0.z) | ((unsigned)f2bf(v0.w) << 16);
        o.z = (unsigned)f2bf(v1.x) | ((unsigned)f2bf(v1.y) << 16);
        o.w = (unsigned)f2bf(v1.z) | ((unsigned)f2bf(v1.w) << 16);
        *(uint4*)(xb + i) = o;
    } else {
        int idx = blockIdx.x * 256 + threadIdx.x;          // 0..2M
        const float* src = (idx >> 20) ? wk : wq;
        ushort_t* dst = (idx >> 20) ? wkT : wqT;
        int id2 = idx & 1048575;
        int nrow = id2 >> 10, k = id2 & 1023;
        dst[id2] = f2bf(src[k * 1024 + nrow]);
    }
}

// ---------- MFMA bf16 GEMM (m97-style global_load_lds staging) ----------
__global__ __launch_bounds__(256) void gemm_qk_kernel(
    const ushort_t* __restrict__ xb, const ushort_t* __restrict__ wqT, const ushort_t* __restrict__ wkT,
    const float* __restrict__ bq, const float* __restrict__ bk,
    ushort_t* __restrict__ Qb, ushort_t* __restrict__ Kb)
{
    const int bm = blockIdx.x;          // 128 M-tiles of 128
    const int bn = blockIdx.y;          // 8 N-tiles of 128
    const int mat = blockIdx.z;         // 0=Q, 1=K
    const ushort_t* W = mat ? wkT : wqT;
    const float* bias = mat ? bk : bq;
    ushort_t* Out = mat ? Kb : Qb;
    const float postscale = mat ? 1.0f : 0.08838834764831845f;

    __shared__ ushort_t a_lds[128 * 32];
    __shared__ ushort_t b_lds[128 * 32];

    const int tid = threadIdx.x;
    const int lane = tid & 63;
    const int wave = tid >> 6;
    const int wr = wave >> 1, wc = wave & 1;
    const int l16 = lane & 15, quad = lane >> 4;

    floatx4 acc[4][4];
    const floatx4 zero4 = {0.f, 0.f, 0.f, 0.f};
#pragma unroll
    for (int i = 0; i < 4; ++i)
#pragma unroll
        for (int j = 0; j < 4; ++j) acc[i][j] = zero4;

    const int srow = wave * 32 + (lane >> 2);
    const int skof = (lane & 3) * 8;
    const ushort_t* gA = xb + (size_t)(bm * 128 + srow) * 1024 + skof;
    const ushort_t* gB = W + (size_t)(bn * 128 + srow) * 1024 + skof;
    ushort_t* lA = &a_lds[wave * 1024];
    ushort_t* lB = &b_lds[wave * 1024];

    for (int kt = 0; kt < 32; ++kt) {
        const int k0 = kt * 32;
        __syncthreads();
        gll16(gA + k0, lA);
        gll16(gA + k0 + 16 * 1024, lA + 512);
        gll16(gB + k0, lB);
        gll16(gB + k0 + 16 * 1024, lB + 512);
        __syncthreads();
        short8 afr[4], bfr[4];
#pragma unroll
        for (int mi = 0; mi < 4; ++mi)
            afr[mi] = *(const short8*)&a_lds[(wr * 64 + mi * 16 + l16) * 32 + quad * 8];
#pragma unroll
        for (int ni = 0; ni < 4; ++ni)
            bfr[ni] = *(const short8*)&b_lds[(wc * 64 + ni * 16 + l16) * 32 + quad * 8];
#pragma unroll
        for (int mi = 0; mi < 4; ++mi)
#pragma unroll
            for (int ni = 0; ni < 4; ++ni)
                acc[mi][ni] = __builtin_amdgcn_mfma_f32_16x16x32_bf16(afr[mi], bfr[ni], acc[mi][ni], 0, 0, 0);
    }
#pragma unroll
    for (int mi = 0; mi < 4; ++mi) {
#pragma unroll
        for (int ni = 0; ni < 4; ++ni) {
            const int gcol = bn * 128 + wc * 64 + ni * 16 + l16;
            const int h = gcol >> 7, d = gcol & 127;
#pragma unroll
            for (int r = 0; r < 4; ++r) {
                const int grow = bm * 128 + wr * 64 + mi * 16 + quad * 4 + r;
                const int b = grow >> 10, s = grow & 1023;
                Out[(((size_t)(b * 8 + h)) * 1024 + s) * 128 + d] =
                    f2bf((acc[mi][ni][r] + bias[gcol]) * postscale);
            }
        }
    }
}

// ---------- attention column sums via MFMA, double-buffered DMA staging ----------
__global__ __launch_bounds__(256) void attn_mfma_kernel(
    const ushort_t* __restrict__ Qb,   // [bh][1024][128] bf16 (scaled)
    const ushort_t* __restrict__ Kb,   // [bh][1024][128] bf16
    float* __restrict__ wout)          // [bh][1024], zero-init
{
    const int bh = blockIdx.x;         // 128
    const int qt = blockIdx.y;         // 8 q-tiles of 128 rows
    __shared__ ushort_t ks[2][128 * 128]; // 2 x 32 KB, XOR-swizzled 16B granules

    const int tid = threadIdx.x;
    const int wave = tid >> 6, lane = tid & 63;
    const int l16 = lane & 15, quad = lane >> 4;

    const ushort_t* Ksrc = Kb + (size_t)bh * 1024 * 128;

    int srcoff[8];
#pragma unroll
    for (int c = 0; c < 8; ++c) {
        int r = wave * 32 + c * 4 + (lane >> 4);
        int g = (lane & 15) ^ (r & 15);
        srcoff[c] = r * 128 + g * 8;
    }

    auto issue = [&](int buf, int kt) {
        const ushort_t* src = Ksrc + (size_t)kt * 16384;
#pragma unroll
        for (int c = 0; c < 8; ++c)
            gll16(src + srcoff[c], &ks[buf][(wave * 8 + c) * 512]);
    };

    short8 aq[2][4];
    {
        const ushort_t* qsrc = Qb + ((size_t)bh * 1024 + qt * 128 + wave * 32) * 128;
#pragma unroll
        for (int mi = 0; mi < 2; ++mi)
#pragma unroll
            for (int ksp = 0; ksp < 4; ++ksp)
                aq[mi][ksp] = *(const short8*)(qsrc + (size_t)(mi * 16 + l16) * 128 + ksp * 32 + quad * 8);
    }

    const floatx4 zero4 = {0.f, 0.f, 0.f, 0.f};
    float lsum[2][4];
#pragma unroll
    for (int mi = 0; mi < 2; ++mi)
#pragma unroll
        for (int r = 0; r < 4; ++r) lsum[mi][r] = 0.f;

    issue(0, 0);

    // ---- pass 1: row sums of exp(s) ----
    for (int kt = 0; kt < 8; ++kt) {
        __syncthreads();
        if (kt < 7) issue((kt + 1) & 1, kt + 1);
        const ushort_t* kbuf = ks[kt & 1];
        floatx4 acc[2][8];
#pragma unroll
        for (int mi = 0; mi < 2; ++mi)
#pragma unroll
            for (int ni = 0; ni < 8; ++ni) acc[mi][ni] = zero4;
#pragma unroll
        for (int ksp = 0; ksp < 4; ++ksp) {
            short8 bk[8];
#pragma unroll
            for (int ni = 0; ni < 8; ++ni) {
                int n = ni * 16 + l16;
                int gs = (ksp * 4 + quad) ^ (n & 15);
                bk[ni] = *(const short8*)&kbuf[n * 128 + gs * 8];
            }
#pragma unroll
            for (int mi = 0; mi < 2; ++mi)
#pragma unroll
                for (int ni = 0; ni < 8; ++ni)
                    acc[mi][ni] = __builtin_amdgcn_mfma_f32_16x16x32_bf16(aq[mi][ksp], bk[ni], acc[mi][ni], 0, 0, 0);
        }
#pragma unroll
        for (int mi = 0; mi < 2; ++mi)
#pragma unroll
            for (int r = 0; r < 4; ++r) {
                float s = 0.f;
#pragma unroll
                for (int ni = 0; ni < 8; ++ni) s += __expf(acc[mi][ni][r]);
                lsum[mi][r] += s;
            }
    }

    issue(0, 0);    // prefetch pass-2 tile 0

    float invl[2][4];
#pragma unroll
    for (int mi = 0; mi < 2; ++mi)
#pragma unroll
        for (int r = 0; r < 4; ++r) {
            float s = lsum[mi][r];
#pragma unroll
            for (int off = 1; off < 16; off <<= 1) s += __shfl_xor(s, off, 16);
            invl[mi][r] = 1.f / s;
        }

    // ---- pass 2: column sums of exp(s)/l ----
    for (int kt = 0; kt < 8; ++kt) {
        __syncthreads();
        if (kt < 7) issue((kt + 1) & 1, kt + 1);
        const ushort_t* kbuf = ks[kt & 1];
        floatx4 acc[2][8];
#pragma unroll
        for (int mi = 0; mi < 2; ++mi)
#pragma unroll
            for (int ni = 0; ni < 8; ++ni) acc[mi][ni] = zero4;
#pragma unroll
        for (int ksp = 0; ksp < 4; ++ksp) {
            short8 bk[8];
#pragma unroll
            for (int ni = 0; ni < 8; ++ni) {
                int n = ni * 16 + l16;
                int gs = (ksp * 4 + quad) ^ (n & 15);
                bk[ni] = *(const short8*)&kbuf[n * 128 + gs * 8];
            }
#pragma unroll
            for (int mi = 0; mi < 2; ++mi)
#pragma unroll
                for (int ni = 0; ni < 8; ++ni)
                    acc[mi][ni] = __builtin_amdgcn_mfma_f32_16x16x32_bf16(aq[mi][ksp], bk[ni], acc[mi][ni], 0, 0, 0);
        }
#pragma unroll
        for (int ni = 0; ni < 8; ++ni) {
            float s = 0.f;
#pragma unroll
            for (int mi = 0; mi < 2; ++mi)
#pragma unroll
                for (int r = 0; r < 4; ++r)
                    s += __expf(acc[mi][ni][r]) * invl[mi][r];
            s += __shfl_xor(s, 16, 64);
            s += __shfl_xor(s, 32, 64);
            if (quad == 0) atomicAdd(&wout[bh * 1024 + kt * 128 + ni * 16 + l16], s);
        }
    }
}

// ---------- u[b,h,:] = sum_k w[b,h,k] * x[b,k,:] ----------
__global__ __launch_bounds__(256) void u_kernel(const float* __restrict__ x,
                                                const float* __restrict__ w,
                                                float* __restrict__ u)
{
    const int b = blockIdx.x, kc = blockIdx.y;
    const int c4 = threadIdx.x;
    const float4* X4 = (const float4*)(x + ((size_t)(b * 1024 + kc * 64)) * 1024);
    float4 acc[8];
#pragma unroll
    for (int h = 0; h < 8; ++h) acc[h] = make_float4(0.f, 0.f, 0.f, 0.f);
    const float* wb = w + b * 8 * 1024 + kc * 64;
    for (int k = 0; k < 64; ++k) {
        float4 xv = X4[(size_t)k * 256 + c4];
#pragma unroll
        for (int h = 0; h < 8; ++h) {
            float ww = wb[h * 1024 + k];
            acc[h].x = fmaf(ww, xv.x, acc[h].x);
            acc[h].y = fmaf(ww, xv.y, acc[h].y);
            acc[h].z = fmaf(ww, xv.z, acc[h].z);
            acc[h].w = fmaf(ww, xv.w, acc[h].w);
        }
    }
#pragma unroll
    for (int h = 0; h < 8; ++h) {
        float* dst = u + ((size_t)(b * 8 + h)) * 1024 + c4 * 4;
        atomicAdd(dst + 0, acc[h].x);
        atomicAdd(dst + 1, acc[h].y);
        atomicAdd(dst + 2, acc[h].z);
        atomicAdd(dst + 3, acc[h].w);
    }
}

// ---------- small GEMM with split-K ----------
__global__ __launch_bounds__(256) void sgemm_kernel(
    const float* __restrict__ A, int lda, long sAz,
    const float* __restrict__ Bm, int ldb, long sBz,
    const float* __restrict__ bias, long sBiasz,
    float* __restrict__ C, int ldc, long sCz,
    int M, int N, int K, float alpha, int nks)
{
    const int z = blockIdx.z;
    const int ks = blockIdx.x % nks;
    const int mt = blockIdx.x / nks;
    const int Kc = K / nks;
    A += (size_t)z * sAz;
    Bm += (size_t)z * sBz;
    C += (size_t)z * sCz;
    const float* bptr = bias ? bias + (size_t)z * sBiasz : nullptr;
    __shared__ float As[64 * 36];
    __shared__ float Bs[32 * 68];
    const int tid = threadIdx.x;
    const int row0 = mt * 64, col0 = blockIdx.y * 64;
    const int ty = tid >> 4, tx = tid & 15;
    float acc[4][4] = {};
    const int aflat = tid * 8;
    const int ar = aflat >> 5, ac = aflat & 31;
    const int br = aflat >> 6, bc = aflat & 63;
    for (int k0 = ks * Kc; k0 < (ks + 1) * Kc; k0 += 32) {
        __syncthreads();
        float4 va0 = make_float4(0.f, 0.f, 0.f, 0.f), va1 = va0;
        if (row0 + ar < M) {
            const float* src = A + (size_t)(row0 + ar) * lda + k0 + ac;
            va0 = *(const float4*)src;
            va1 = *(const float4*)(src + 4);
        }
        *(float4*)&As[ar * 36 + ac] = va0;
        *(float4*)&As[ar * 36 + ac + 4] = va1;
        {
            const float* srcb = Bm + (size_t)(k0 + br) * ldb + col0 + bc;
            *(float4*)&Bs[br * 68 + bc] = *(const float4*)srcb;
            *(float4*)&Bs[br * 68 + bc + 4] = *(const float4*)(srcb + 4);
        }
        __syncthreads();
#pragma unroll
        for (int kk = 0; kk < 32; ++kk) {
            float a0 = As[(ty * 4 + 0) * 36 + kk];
            float a1 = As[(ty * 4 + 1) * 36 + kk];
            float a2 = As[(ty * 4 + 2) * 36 + kk];
            float a3 = As[(ty * 4 + 3) * 36 + kk];
            float b0 = Bs[kk * 68 + tx * 4 + 0];
            float b1 = Bs[kk * 68 + tx * 4 + 1];
            float b2 = Bs[kk * 68 + tx * 4 + 2];
            float b3 = Bs[kk * 68 + tx * 4 + 3];
            acc[0][0] = fmaf(a0, b0, acc[0][0]); acc[0][1] = fmaf(a0, b1, acc[0][1]);
            acc[0][2] = fmaf(a0, b2, acc[0][2]); acc[0][3] = fmaf(a0, b3, acc[0][3]);
            acc[1][0] = fmaf(a1, b0, acc[1][0]); acc[1][1] = fmaf(a1, b1, acc[1][1]);
            acc[1][2] = fmaf(a1, b2, acc[1][2]); acc[1][3] = fmaf(a1, b3, acc[1][3]);
            acc[2][0] = fmaf(a2, b0, acc[2][0]); acc[2][1] = fmaf(a2, b1, acc[2][1]);
            acc[2][2] = fmaf(a2, b2, acc[2][2]); acc[2][3] = fmaf(a2, b3, acc[2][3]);
            acc[3][0] = fmaf(a3, b0, acc[3][0]); acc[3][1] = fmaf(a3, b1, acc[3][1]);
            acc[3][2] = fmaf(a3, b2, acc[3][2]); acc[3][3] = fmaf(a3, b3, acc[3][3]);
        }
    }
#pragma unroll
    for (int i = 0; i < 4; ++i) {
        int r = row0 + ty * 4 + i;
        if (r >= M) continue;
#pragma unroll
        for (int j = 0; j < 4; ++j) {
            int c = col0 + tx * 4 + j;
            float v = alpha * acc[i][j] + ((bptr && ks == 0) ? bptr[c] : 0.f);
            if (nks > 1) atomicAdd(&C[(size_t)r * ldc + c], v);
            else C[(size_t)r * ldc + c] = v;
        }
    }
}

// ---------- fused gate: h1=tanh -> logits -> softmax -> DR = rw @ emb ----------
__global__ __launch_bounds__(256) void gate_kernel(
    const float* __restrict__ Ge, const float* __restrict__ Ee, const float* __restrict__ rg_b1,
    const float* __restrict__ rg_w2, const float* __restrict__ rg_b2,
    const float* __restrict__ emb, float* __restrict__ DR)
{
    const int row = blockIdx.x;       // 1024 = b*64+n
    const int b = row >> 6, n = row & 63;
    __shared__ float h[1024];
    __shared__ float red[256];
    __shared__ float rw[64];
    const int tid = threadIdx.x;
    for (int c = tid; c < 1024; c += 256)
        h[c] = tanhf(Ge[b * 1024 + c] + Ee[n * 1024 + c] + rg_b1[c]);
    __syncthreads();
    const int j = tid & 63, ch = tid >> 6;
    float part = 0.f;
    const float* w2p = rg_w2 + (size_t)(ch * 256) * 64 + j;
    for (int c = 0; c < 256; ++c)
        part = fmaf(h[ch * 256 + c], w2p[c * 64], part);
    red[tid] = part;
    __syncthreads();
    if (tid < 64) {
        float lg = red[tid] + red[tid + 64] + red[tid + 128] + red[tid + 192] + rg_b2[j];
        float m = lg;
#pragma unroll
        for (int off = 1; off < 64; off <<= 1) m = fmaxf(m, __shfl_xor(m, off, 64));
        float e = __expf(lg - m);
        float s = e;
#pragma unroll
        for (int off = 1; off < 64; off <<= 1) s += __shfl_xor(s, off, 64);
        rw[tid] = e / s;
    }
    __syncthreads();
    float4 acc = make_float4(0.f, 0.f, 0.f, 0.f);
    const float4* E4 = (const float4*)emb;
    for (int nn = 0; nn < 64; ++nn) {
        float wv = rw[nn];
        float4 ev = E4[nn * 256 + tid];
        acc.x = fmaf(wv, ev.x, acc.x);
        acc.y = fmaf(wv, ev.y, acc.y);
        acc.z = fmaf(wv, ev.z, acc.z);
        acc.w = fmaf(wv, ev.w, acc.w);
    }
    *(float4*)&DR[(size_t)row * 1024 + tid * 4] = acc;
}

// ---------- heads part 1: split-K partial GEMM ----------
// grid (64 n, 2 task, 8 ksl). hpart[ksl][task][n][b][j] = sum_{c in slice} comb[b][c]*W1[c][j]
__global__ __launch_bounds__(256) void heads_p1_kernel(
    const float* __restrict__ g, const float* __restrict__ DR,
    const float* __restrict__ rw1, const float* __restrict__ cw1,
    float* __restrict__ hpart)
{
    const int n = blockIdx.x, task = blockIdx.y, ksl = blockIdx.z;
    __shared__ float combs[16 * 128];   // 8 KB: comb slice [b][c]
    const int tid = threadIdx.x;
    for (int i = tid; i < 2048; i += 256) {
        int b = i >> 7, c = i & 127;
        int gc = ksl * 128 + c;
        combs[i] = g[b * 1024 + gc] + DR[((size_t)(b * 64 + n)) * 1024 + gc];
    }
    __syncthreads();
    const int j = tid & 127, sub = tid >> 7;   // 2 subs x 8 b
    const float* W1 = (task ? cw1 : rw1) + (size_t)n * 131072 + (size_t)ksl * 128 * 128;
    float a[8] = {};
    for (int c4 = 0; c4 < 32; ++c4) {
        const float w0 = W1[(c4 * 4 + 0) * 128 + j];
        const float w1 = W1[(c4 * 4 + 1) * 128 + j];
        const float w2 = W1[(c4 * 4 + 2) * 128 + j];
        const float w3 = W1[(c4 * 4 + 3) * 128 + j];
#pragma unroll
        for (int bb = 0; bb < 8; ++bb) {
            float4 cv = *(const float4*)&combs[(sub * 8 + bb) * 128 + c4 * 4];
            a[bb] = fmaf(cv.x, w0, a[bb]);
            a[bb] = fmaf(cv.y, w1, a[bb]);
            a[bb] = fmaf(cv.z, w2, a[bb]);
            a[bb] = fmaf(cv.w, w3, a[bb]);
        }
    }
    float* dst = hpart + (((size_t)(ksl * 2 + task) * 64 + n) * 16 + sub * 8) * 128 + j;
#pragma unroll
    for (int bb = 0; bb < 8; ++bb) dst[bb * 128] = a[bb];
}

// ---------- heads part 2: reduce partials, ReLU, dot W2, activation ----------
// grid (64 n, 2 task), 256 threads = 16 b x 16 j-groups of 8
__global__ __launch_bounds__(256) void heads_p2_kernel(
    const float* __restrict__ hpart,
    const float* __restrict__ rb1, const float* __restrict__ rw2, const float* __restrict__ rb2,
    const float* __restrict__ cb1, const float* __restrict__ cw2, const float* __restrict__ cb2,
    float* __restrict__ out)
{
    const int n = blockIdx.x, task = blockIdx.y;
    const int tid = threadIdx.x;
    const int b = tid >> 4, jg = tid & 15;
    const float* b1 = (task ? cb1 : rb1) + n * 128 + jg * 8;
    const float* W2 = (task ? cw2 : rw2) + n * 128 + jg * 8;
    float s = 0.f;
#pragma unroll
    for (int k = 0; k < 8; ++k) {
        float h = b1[k];
#pragma unroll
        for (int ksl = 0; ksl < 8; ++ksl)
            h += hpart[(((size_t)(ksl * 2 + task) * 64 + n) * 16 + b) * 128 + jg * 8 + k];
        s = fmaf(fmaxf(h, 0.f), W2[k], s);
    }
#pragma unroll
    for (int off = 1; off < 16; off <<= 1) s += __shfl_xor(s, off, 16);
    if (jg == 0) {
        s += (task ? cb2 : rb2)[n];
        float r = task ? (1.f / (1.f + __expf(-s)))
                       : (fmaxf(s, 0.f) + log1pf(__expf(-fabsf(s))));
        out[task * 1024 + b * 64 + n] = r;
    }
}

// ---------- launch ----------
extern "C" void kernel_launch(void* const* d_in, const int* in_sizes, int n_in,
                              void* d_out, int out_size, void* d_ws, size_t ws_size,
                              hipStream_t stream)
{
    const float* x      = (const float*)d_in[0];
    const float* wq     = (const float*)d_in[1];
    const float* bq     = (const float*)d_in[2];
    const float* wk     = (const float*)d_in[3];
    const float* bk     = (const float*)d_in[4];
    const float* wv     = (const float*)d_in[5];
    const float* bv     = (const float*)d_in[6];
    const float* wo     = (const float*)d_in[7];
    const float* bo     = (const float*)d_in[8];
    const float* emb    = (const float*)d_in[9];
    const float* rg_w1  = (const float*)d_in[10];
    const float* rg_b1  = (const float*)d_in[11];
    const float* rg_w2  = (const float*)d_in[12];
    const float* rg_b2  = (const float*)d_in[13];
    const float* reg_w1 = (const float*)d_in[14];
    const float* reg_b1 = (const float*)d_in[15];
    const float* reg_w2 = (const float*)d_in[16];
    const float* reg_b2 = (const float*)d_in[17];
    const float* cls_w1 = (const float*)d_in[18];
    const float* cls_b1 = (const float*)d_in[19];
    const float* cls_w2 = (const float*)d_in[20];
    const float* cls_b2 = (const float*)d_in[21];

    char* ws = (char*)d_ws;
    size_t off = 0;
    auto alloc = [&](size_t bytes) { size_t cur = off; off += (bytes + 255) & ~(size_t)255; return cur; };

    ushort_t* xb  = (ushort_t*)(ws + alloc((size_t)16777216 * 2));
    ushort_t* wqT = (ushort_t*)(ws + alloc((size_t)1048576 * 2));
    ushort_t* wkT = (ushort_t*)(ws + alloc((size_t)1048576 * 2));
    ushort_t* Qb  = (ushort_t*)(ws + alloc((size_t)16777216 * 2));
    ushort_t* Kb  = (ushort_t*)(ws + alloc((size_t)16777216 * 2));
    size_t zero_beg = off;
    float* wcol = (float*)(ws + alloc((size_t)131072 * 4));
    float* u    = (float*)(ws + alloc((size_t)131072 * 4));
    float* cm   = (float*)(ws + alloc((size_t)16384 * 4));
    float* gbuf = (float*)(ws + alloc((size_t)16384 * 4));
    float* Ge   = (float*)(ws + alloc((size_t)16384 * 4));
    float* Ee   = (float*)(ws + alloc((size_t)65536 * 4));
    size_t zero_end = off;
    float* DR    = (float*)(ws + alloc((size_t)1048576 * 4));
    float* hpart = (float*)(ws + alloc((size_t)2097152 * 4));  // [8][2][64][16][128]

    hipMemsetAsync(ws + zero_beg, 0, zero_end - zero_beg, stream);

    prep_kernel<<<dim3(8192, 2), 256, 0, stream>>>(x, xb, wq, wk, wqT, wkT);
    gemm_qk_kernel<<<dim3(128, 8, 2), 256, 0, stream>>>(xb, wqT, wkT, bq, bk, Qb, Kb);
    attn_mfma_kernel<<<dim3(128, 8), 256, 0, stream>>>(Qb, Kb, wcol);
    u_kernel<<<dim3(16, 16), 256, 0, stream>>>(x, wcol, u);
    sgemm_kernel<<<dim3(4, 2, 8), 256, 0, stream>>>(u, 8192, 1024, wv, 1024, 128, bv, 128,
                                                    cm, 1024, 128, 16, 128, 1024, 1.f / 1024.f, 4);
    sgemm_kernel<<<dim3(8, 16, 1), 256, 0, stream>>>(cm, 1024, 0, wo, 1024, 0, bo, 0,
                                                     gbuf, 1024, 0, 16, 1024, 1024, 1.f, 8);
    sgemm_kernel<<<dim3(8, 16, 1), 256, 0, stream>>>(gbuf, 1024, 0, rg_w1, 1024, 0, nullptr, 0,
                                                     Ge, 1024, 0, 16, 1024, 1024, 1.f, 8);
    sgemm_kernel<<<dim3(8, 16, 1), 256, 0, stream>>>(emb, 1024, 0, rg_w1 + (size_t)1048576, 1024, 0, nullptr, 0,
                                                     Ee, 1024, 0, 64, 1024, 1024, 1.f, 8);
    gate_kernel<<<1024, 256, 0, stream>>>(Ge, Ee, rg_b1, rg_w2, rg_b2, emb, DR);
    heads_p1_kernel<<<dim3(64, 2, 8), 256, 0, stream>>>(gbuf, DR, reg_w1, cls_w1, hpart);
    heads_p2_kernel<<<dim3(64, 2), 256, 0, stream>>>(hpart, reg_b1, reg_w2, reg_b2,
                                                     cls_b1, cls_w2, cls_b2, (float*)d_out);
    (void)in_sizes; (void)n_in; (void)out_size; (void)ws_size;
}

// Round 6
// 523.447 us; speedup vs baseline: 1.2810x; 1.0745x over previous
//
#include <hip/hip_runtime.h>

typedef unsigned short ushort_t;
typedef __attribute__((ext_vector_type(8))) short short8;
typedef __attribute__((ext_vector_type(4))) float floatx4;

// ---------- helpers ----------
__device__ __forceinline__ ushort_t f2bf(float f) {
    unsigned u = __float_as_uint(f);
    return (ushort_t)((u + 0x7fffu + ((u >> 16) & 1u)) >> 16);
}
__device__ __forceinline__ void gll16(const void* g, void* l) {
    __builtin_amdgcn_global_load_lds(
        (const __attribute__((address_space(1))) unsigned int*)g,
        (__attribute__((address_space(3))) unsigned int*)l, 16, 0, 0);
}

// ---------- cast x -> bf16 ----------
__global__ void prep_kernel(const float* __restrict__ x, ushort_t* __restrict__ xb) {
    size_t i = ((size_t)blockIdx.x * 256 + threadIdx.x) * 8;
    float4 v0 = *(const float4*)(x + i);
    float4 v1 = *(const float4*)(x + i + 4);
    uint4 o;
    o.x = (unsigned)f2bf(v0.x) | ((unsigned)f2bf(v0.y) << 16);
    o.y = (unsigned)f2bf(v0.z) | ((unsigned)f2bf(v0.w) << 16);
    o.z = (unsigned)f2bf(v1.x) | ((unsigned)f2bf(v1.y) << 16);
    o.w = (unsigned)f2bf(v1.z) | ((unsigned)f2bf(v1.w) << 16);
    *(uint4*)(xb + i) = o;
}

// ---------- LDS-tiled transpose+cast: out[n][k] = bf16(w[k][n]) ----------
__global__ __launch_bounds__(256) void transpose_kernel(
    const float* __restrict__ wq, const float* __restrict__ wk,
    ushort_t* __restrict__ wqT, ushort_t* __restrict__ wkT)
{
    const float* src = blockIdx.z ? wk : wq;
    ushort_t* dst = blockIdx.z ? wkT : wqT;
    const int k0 = blockIdx.x * 64, n0 = blockIdx.y * 64;
    __shared__ float t[64][65];
    const int tid = threadIdx.x;
    const int rr = tid >> 4, cc = (tid & 15) * 4;
#pragma unroll
    for (int p = 0; p < 4; ++p) {
        float4 v = *(const float4*)(src + (size_t)(k0 + p * 16 + rr) * 1024 + n0 + cc);
        t[p * 16 + rr][cc + 0] = v.x;
        t[p * 16 + rr][cc + 1] = v.y;
        t[p * 16 + rr][cc + 2] = v.z;
        t[p * 16 + rr][cc + 3] = v.w;
    }
    __syncthreads();
#pragma unroll
    for (int p = 0; p < 4; ++p) {
        int nl = p * 16 + rr;
        uint2 o;
        o.x = (unsigned)f2bf(t[cc + 0][nl]) | ((unsigned)f2bf(t[cc + 1][nl]) << 16);
        o.y = (unsigned)f2bf(t[cc + 2][nl]) | ((unsigned)f2bf(t[cc + 3][nl]) << 16);
        *(uint2*)(dst + (size_t)(n0 + nl) * 1024 + k0 + cc) = o;
    }
}

// ---------- MFMA bf16 GEMM, double-buffered DMA staging ----------
__global__ __launch_bounds__(256) void gemm_qk_kernel(
    const ushort_t* __restrict__ xb, const ushort_t* __restrict__ wqT, const ushort_t* __restrict__ wkT,
    const float* __restrict__ bq, const float* __restrict__ bk,
    ushort_t* __restrict__ Qb, ushort_t* __restrict__ Kb)
{
    const int bm = blockIdx.x;          // 128 M-tiles of 128
    const int bn = blockIdx.y;          // 8 N-tiles of 128
    const int mat = blockIdx.z;         // 0=Q, 1=K
    const ushort_t* W = mat ? wkT : wqT;
    const float* bias = mat ? bk : bq;
    ushort_t* Out = mat ? Kb : Qb;
    const float postscale = mat ? 1.0f : 0.08838834764831845f;

    __shared__ ushort_t a_lds[2][128 * 32];   // 2 x 8 KB
    __shared__ ushort_t b_lds[2][128 * 32];

    const int tid = threadIdx.x;
    const int lane = tid & 63;
    const int wave = tid >> 6;
    const int wr = wave >> 1, wc = wave & 1;
    const int l16 = lane & 15, quad = lane >> 4;

    floatx4 acc[4][4];
    const floatx4 zero4 = {0.f, 0.f, 0.f, 0.f};
#pragma unroll
    for (int i = 0; i < 4; ++i)
#pragma unroll
        for (int j = 0; j < 4; ++j) acc[i][j] = zero4;

    const int srow = wave * 32 + (lane >> 2);
    const int skof = (lane & 3) * 8;
    const ushort_t* gA = xb + (size_t)(bm * 128 + srow) * 1024 + skof;
    const ushort_t* gB = W + (size_t)(bn * 128 + srow) * 1024 + skof;

    auto issue = [&](int buf, int k0) {
        ushort_t* lA = &a_lds[buf][wave * 1024];
        ushort_t* lB = &b_lds[buf][wave * 1024];
        gll16(gA + k0, lA);
        gll16(gA + k0 + 16 * 1024, lA + 512);
        gll16(gB + k0, lB);
        gll16(gB + k0 + 16 * 1024, lB + 512);
    };

    issue(0, 0);
    for (int kt = 0; kt < 32; ++kt) {
        __syncthreads();
        if (kt < 31) issue((kt + 1) & 1, (kt + 1) * 32);
        const ushort_t* la = a_lds[kt & 1];
        const ushort_t* lb = b_lds[kt & 1];
        short8 afr[4], bfr[4];
#pragma unroll
        for (int mi = 0; mi < 4; ++mi)
            afr[mi] = *(const short8*)&la[(wr * 64 + mi * 16 + l16) * 32 + quad * 8];
#pragma unroll
        for (int ni = 0; ni < 4; ++ni)
            bfr[ni] = *(const short8*)&lb[(wc * 64 + ni * 16 + l16) * 32 + quad * 8];
#pragma unroll
        for (int mi = 0; mi < 4; ++mi)
#pragma unroll
            for (int ni = 0; ni < 4; ++ni)
                acc[mi][ni] = __builtin_amdgcn_mfma_f32_16x16x32_bf16(afr[mi], bfr[ni], acc[mi][ni], 0, 0, 0);
    }
#pragma unroll
    for (int mi = 0; mi < 4; ++mi) {
#pragma unroll
        for (int ni = 0; ni < 4; ++ni) {
            const int gcol = bn * 128 + wc * 64 + ni * 16 + l16;
            const int h = gcol >> 7, d = gcol & 127;
#pragma unroll
            for (int r = 0; r < 4; ++r) {
                const int grow = bm * 128 + wr * 64 + mi * 16 + quad * 4 + r;
                const int b = grow >> 10, s = grow & 1023;
                Out[(((size_t)(b * 8 + h)) * 1024 + s) * 128 + d] =
                    f2bf((acc[mi][ni][r] + bias[gcol]) * postscale);
            }
        }
    }
}

// ---------- attention column sums via MFMA, 64-row K-tiles, dbuf DMA ----------
__global__ __launch_bounds__(256, 4) void attn_mfma_kernel(
    const ushort_t* __restrict__ Qb,   // [bh][1024][128] bf16 (scaled)
    const ushort_t* __restrict__ Kb,   // [bh][1024][128] bf16
    float* __restrict__ wout)          // [bh][1024], zero-init
{
    const int bh = blockIdx.x;         // 128
    const int qt = blockIdx.y;         // 8 q-tiles of 128 rows
    __shared__ ushort_t ks[2][64 * 128]; // 2 x 16 KB, XOR-swizzled 16B granules

    const int tid = threadIdx.x;
    const int wave = tid >> 6, lane = tid & 63;
    const int l16 = lane & 15, quad = lane >> 4;

    const ushort_t* Ksrc = Kb + (size_t)bh * 1024 * 128;

    // inverse-swizzled per-lane source offsets: call c covers LDS rows
    // wave*16+c*4+(lane>>4); content col-group g = (lane&15) ^ (row&15)
    int srcoff[4];
#pragma unroll
    for (int c = 0; c < 4; ++c) {
        int r = wave * 16 + c * 4 + (lane >> 4);
        int g = (lane & 15) ^ (r & 15);
        srcoff[c] = r * 128 + g * 8;
    }

    auto issue = [&](int buf, int kt) {
        const ushort_t* src = Ksrc + (size_t)kt * 8192;
#pragma unroll
        for (int c = 0; c < 4; ++c)
            gll16(src + srcoff[c], &ks[buf][(wave * 4 + c) * 512]);
    };

    // Q fragments, kept in registers for both passes
    short8 aq[2][4];
    {
        const ushort_t* qsrc = Qb + ((size_t)bh * 1024 + qt * 128 + wave * 32) * 128;
#pragma unroll
        for (int mi = 0; mi < 2; ++mi)
#pragma unroll
            for (int ksp = 0; ksp < 4; ++ksp)
                aq[mi][ksp] = *(const short8*)(qsrc + (size_t)(mi * 16 + l16) * 128 + ksp * 32 + quad * 8);
    }

    const floatx4 zero4 = {0.f, 0.f, 0.f, 0.f};
    float lsum[2][4];
#pragma unroll
    for (int mi = 0; mi < 2; ++mi)
#pragma unroll
        for (int r = 0; r < 4; ++r) lsum[mi][r] = 0.f;

    issue(0, 0);

    // ---- pass 1: row sums of exp(s) ----
    for (int kt = 0; kt < 16; ++kt) {
        __syncthreads();
        if (kt < 15) issue((kt + 1) & 1, kt + 1);
        const ushort_t* kbuf = ks[kt & 1];
        floatx4 acc[2][4];
#pragma unroll
        for (int mi = 0; mi < 2; ++mi)
#pragma unroll
            for (int ni = 0; ni < 4; ++ni) acc[mi][ni] = zero4;
#pragma unroll
        for (int ksp = 0; ksp < 4; ++ksp) {
            short8 bk[4];
#pragma unroll
            for (int ni = 0; ni < 4; ++ni) {
                int n = ni * 16 + l16;
                int gs = (ksp * 4 + quad) ^ (n & 15);
                bk[ni] = *(const short8*)&kbuf[n * 128 + gs * 8];
            }
#pragma unroll
            for (int mi = 0; mi < 2; ++mi)
#pragma unroll
                for (int ni = 0; ni < 4; ++ni)
                    acc[mi][ni] = __builtin_amdgcn_mfma_f32_16x16x32_bf16(aq[mi][ksp], bk[ni], acc[mi][ni], 0, 0, 0);
        }
#pragma unroll
        for (int mi = 0; mi < 2; ++mi)
#pragma unroll
            for (int r = 0; r < 4; ++r) {
                float s = 0.f;
#pragma unroll
                for (int ni = 0; ni < 4; ++ni) s += __expf(acc[mi][ni][r]);
                lsum[mi][r] += s;
            }
    }

    issue(0, 0);    // prefetch pass-2 tile 0 (buf0's last readers finished before kt=15's barrier)

    float invl[2][4];
#pragma unroll
    for (int mi = 0; mi < 2; ++mi)
#pragma unroll
        for (int r = 0; r < 4; ++r) {
            float s = lsum[mi][r];
#pragma unroll
            for (int off = 1; off < 16; off <<= 1) s += __shfl_xor(s, off, 16);
            invl[mi][r] = 1.f / s;
        }

    // ---- pass 2: column sums of exp(s)/l ----
    for (int kt = 0; kt < 16; ++kt) {
        __syncthreads();
        if (kt < 15) issue((kt + 1) & 1, kt + 1);
        const ushort_t* kbuf = ks[kt & 1];
        floatx4 acc[2][4];
#pragma unroll
        for (int mi = 0; mi < 2; ++mi)
#pragma unroll
            for (int ni = 0; ni < 4; ++ni) acc[mi][ni] = zero4;
#pragma unroll
        for (int ksp = 0; ksp < 4; ++ksp) {
            short8 bk[4];
#pragma unroll
            for (int ni = 0; ni < 4; ++ni) {
                int n = ni * 16 + l16;
                int gs = (ksp * 4 + quad) ^ (n & 15);
                bk[ni] = *(const short8*)&kbuf[n * 128 + gs * 8];
            }
#pragma unroll
            for (int mi = 0; mi < 2; ++mi)
#pragma unroll
                for (int ni = 0; ni < 4; ++ni)
                    acc[mi][ni] = __builtin_amdgcn_mfma_f32_16x16x32_bf16(aq[mi][ksp], bk[ni], acc[mi][ni], 0, 0, 0);
        }
#pragma unroll
        for (int ni = 0; ni < 4; ++ni) {
            float s = 0.f;
#pragma unroll
            for (int mi = 0; mi < 2; ++mi)
#pragma unroll
                for (int r = 0; r < 4; ++r)
                    s += __expf(acc[mi][ni][r]) * invl[mi][r];
            s += __shfl_xor(s, 16, 64);
            s += __shfl_xor(s, 32, 64);
            if (quad == 0) atomicAdd(&wout[bh * 1024 + kt * 64 + ni * 16 + l16], s);
        }
    }
}

// ---------- u[b,h,:] = sum_k w[b,h,k] * xb[b,k,:]  (bf16 x) ----------
__global__ __launch_bounds__(256) void u_kernel(const ushort_t* __restrict__ xb,
                                                const float* __restrict__ w,
                                                float* __restrict__ u)
{
    const int b = blockIdx.x, kc = blockIdx.y;
    const int c4 = threadIdx.x;
    const ushort_t* Xp = xb + ((size_t)(b * 1024 + kc * 64)) * 1024 + c4 * 4;
    float4 acc[8];
#pragma unroll
    for (int h = 0; h < 8; ++h) acc[h] = make_float4(0.f, 0.f, 0.f, 0.f);
    const float* wb = w + b * 8 * 1024 + kc * 64;
    for (int k = 0; k < 64; ++k) {
        uint2 uv = *(const uint2*)(Xp + (size_t)k * 1024);
        float x0 = __uint_as_float(uv.x << 16);
        float x1 = __uint_as_float(uv.x & 0xffff0000u);
        float x2 = __uint_as_float(uv.y << 16);
        float x3 = __uint_as_float(uv.y & 0xffff0000u);
#pragma unroll
        for (int h = 0; h < 8; ++h) {
            float ww = wb[h * 1024 + k];
            acc[h].x = fmaf(ww, x0, acc[h].x);
            acc[h].y = fmaf(ww, x1, acc[h].y);
            acc[h].z = fmaf(ww, x2, acc[h].z);
            acc[h].w = fmaf(ww, x3, acc[h].w);
        }
    }
#pragma unroll
    for (int h = 0; h < 8; ++h) {
        float* dst = u + ((size_t)(b * 8 + h)) * 1024 + c4 * 4;
        atomicAdd(dst + 0, acc[h].x);
        atomicAdd(dst + 1, acc[h].y);
        atomicAdd(dst + 2, acc[h].z);
        atomicAdd(dst + 3, acc[h].w);
    }
}

// ---------- small GEMM with split-K ----------
__global__ __launch_bounds__(256) void sgemm_kernel(
    const float* __restrict__ A, int lda, long sAz,
    const float* __restrict__ Bm, int ldb, long sBz,
    const float* __restrict__ bias, long sBiasz,
    float* __restrict__ C, int ldc, long sCz,
    int M, int N, int K, float alpha, int nks)
{
    const int z = blockIdx.z;
    const int ks = blockIdx.x % nks;
    const int mt = blockIdx.x / nks;
    const int Kc = K / nks;
    A += (size_t)z * sAz;
    Bm += (size_t)z * sBz;
    C += (size_t)z * sCz;
    const float* bptr = bias ? bias + (size_t)z * sBiasz : nullptr;
    __shared__ float As[64 * 36];
    __shared__ float Bs[32 * 68];
    const int tid = threadIdx.x;
    const int row0 = mt * 64, col0 = blockIdx.y * 64;
    const int ty = tid >> 4, tx = tid & 15;
    float acc[4][4] = {};
    const int aflat = tid * 8;
    const int ar = aflat >> 5, ac = aflat & 31;
    const int br = aflat >> 6, bc = aflat & 63;
    for (int k0 = ks * Kc; k0 < (ks + 1) * Kc; k0 += 32) {
        __syncthreads();
        float4 va0 = make_float4(0.f, 0.f, 0.f, 0.f), va1 = va0;
        if (row0 + ar < M) {
            const float* src = A + (size_t)(row0 + ar) * lda + k0 + ac;
            va0 = *(const float4*)src;
            va1 = *(const float4*)(src + 4);
        }
        *(float4*)&As[ar * 36 + ac] = va0;
        *(float4*)&As[ar * 36 + ac + 4] = va1;
        {
            const float* srcb = Bm + (size_t)(k0 + br) * ldb + col0 + bc;
            *(float4*)&Bs[br * 68 + bc] = *(const float4*)srcb;
            *(float4*)&Bs[br * 68 + bc + 4] = *(const float4*)(srcb + 4);
        }
        __syncthreads();
#pragma unroll
        for (int kk = 0; kk < 32; ++kk) {
            float a0 = As[(ty * 4 + 0) * 36 + kk];
            float a1 = As[(ty * 4 + 1) * 36 + kk];
            float a2 = As[(ty * 4 + 2) * 36 + kk];
            float a3 = As[(ty * 4 + 3) * 36 + kk];
            float b0 = Bs[kk * 68 + tx * 4 + 0];
            float b1 = Bs[kk * 68 + tx * 4 + 1];
            float b2 = Bs[kk * 68 + tx * 4 + 2];
            float b3 = Bs[kk * 68 + tx * 4 + 3];
            acc[0][0] = fmaf(a0, b0, acc[0][0]); acc[0][1] = fmaf(a0, b1, acc[0][1]);
            acc[0][2] = fmaf(a0, b2, acc[0][2]); acc[0][3] = fmaf(a0, b3, acc[0][3]);
            acc[1][0] = fmaf(a1, b0, acc[1][0]); acc[1][1] = fmaf(a1, b1, acc[1][1]);
            acc[1][2] = fmaf(a1, b2, acc[1][2]); acc[1][3] = fmaf(a1, b3, acc[1][3]);
            acc[2][0] = fmaf(a2, b0, acc[2][0]); acc[2][1] = fmaf(a2, b1, acc[2][1]);
            acc[2][2] = fmaf(a2, b2, acc[2][2]); acc[2][3] = fmaf(a2, b3, acc[2][3]);
            acc[3][0] = fmaf(a3, b0, acc[3][0]); acc[3][1] = fmaf(a3, b1, acc[3][1]);
            acc[3][2] = fmaf(a3, b2, acc[3][2]); acc[3][3] = fmaf(a3, b3, acc[3][3]);
        }
    }
#pragma unroll
    for (int i = 0; i < 4; ++i) {
        int r = row0 + ty * 4 + i;
        if (r >= M) continue;
#pragma unroll
        for (int j = 0; j < 4; ++j) {
            int c = col0 + tx * 4 + j;
            float v = alpha * acc[i][j] + ((bptr && ks == 0) ? bptr[c] : 0.f);
            if (nks > 1) atomicAdd(&C[(size_t)r * ldc + c], v);
            else C[(size_t)r * ldc + c] = v;
        }
    }
}

// ---------- fused gate: h1=tanh -> logits -> softmax -> DR = rw @ emb ----------
__global__ __launch_bounds__(256) void gate_kernel(
    const float* __restrict__ Ge, const float* __restrict__ Ee, const float* __restrict__ rg_b1,
    const float* __restrict__ rg_w2, const float* __restrict__ rg_b2,
    const float* __restrict__ emb, float* __restrict__ DR)
{
    const int row = blockIdx.x;       // 1024 = b*64+n
    const int b = row >> 6, n = row & 63;
    __shared__ float h[1024];
    __shared__ float red[256];
    __shared__ float rw[64];
    const int tid = threadIdx.x;
    for (int c = tid; c < 1024; c += 256)
        h[c] = tanhf(Ge[b * 1024 + c] + Ee[n * 1024 + c] + rg_b1[c]);
    __syncthreads();
    const int j = tid & 63, ch = tid >> 6;
    float part = 0.f;
    const float* w2p = rg_w2 + (size_t)(ch * 256) * 64 + j;
    for (int c = 0; c < 256; ++c)
        part = fmaf(h[ch * 256 + c], w2p[c * 64], part);
    red[tid] = part;
    __syncthreads();
    if (tid < 64) {
        float lg = red[tid] + red[tid + 64] + red[tid + 128] + red[tid + 192] + rg_b2[j];
        float m = lg;
#pragma unroll
        for (int off = 1; off < 64; off <<= 1) m = fmaxf(m, __shfl_xor(m, off, 64));
        float e = __expf(lg - m);
        float s = e;
#pragma unroll
        for (int off = 1; off < 64; off <<= 1) s += __shfl_xor(s, off, 64);
        rw[tid] = e / s;
    }
    __syncthreads();
    float4 acc = make_float4(0.f, 0.f, 0.f, 0.f);
    const float4* E4 = (const float4*)emb;
    for (int nn = 0; nn < 64; ++nn) {
        float wv = rw[nn];
        float4 ev = E4[nn * 256 + tid];
        acc.x = fmaf(wv, ev.x, acc.x);
        acc.y = fmaf(wv, ev.y, acc.y);
        acc.z = fmaf(wv, ev.z, acc.z);
        acc.w = fmaf(wv, ev.w, acc.w);
    }
    *(float4*)&DR[(size_t)row * 1024 + tid * 4] = acc;
}

// ---------- heads part 1: split-K partial GEMM ----------
__global__ __launch_bounds__(256) void heads_p1_kernel(
    const float* __restrict__ g, const float* __restrict__ DR,
    const float* __restrict__ rw1, const float* __restrict__ cw1,
    float* __restrict__ hpart)
{
    const int n = blockIdx.x, task = blockIdx.y, ksl = blockIdx.z;
    __shared__ float combs[16 * 128];
    const int tid = threadIdx.x;
    for (int i = tid; i < 2048; i += 256) {
        int b = i >> 7, c = i & 127;
        int gc = ksl * 128 + c;
        combs[i] = g[b * 1024 + gc] + DR[((size_t)(b * 64 + n)) * 1024 + gc];
    }
    __syncthreads();
    const int j = tid & 127, sub = tid >> 7;
    const float* W1 = (task ? cw1 : rw1) + (size_t)n * 131072 + (size_t)ksl * 128 * 128;
    float a[8] = {};
    for (int c4 = 0; c4 < 32; ++c4) {
        const float w0 = W1[(c4 * 4 + 0) * 128 + j];
        const float w1 = W1[(c4 * 4 + 1) * 128 + j];
        const float w2 = W1[(c4 * 4 + 2) * 128 + j];
        const float w3 = W1[(c4 * 4 + 3) * 128 + j];
#pragma unroll
        for (int bb = 0; bb < 8; ++bb) {
            float4 cv = *(const float4*)&combs[(sub * 8 + bb) * 128 + c4 * 4];
            a[bb] = fmaf(cv.x, w0, a[bb]);
            a[bb] = fmaf(cv.y, w1, a[bb]);
            a[bb] = fmaf(cv.z, w2, a[bb]);
            a[bb] = fmaf(cv.w, w3, a[bb]);
        }
    }
    float* dst = hpart + (((size_t)(ksl * 2 + task) * 64 + n) * 16 + sub * 8) * 128 + j;
#pragma unroll
    for (int bb = 0; bb < 8; ++bb) dst[bb * 128] = a[bb];
}

// ---------- heads part 2 ----------
__global__ __launch_bounds__(256) void heads_p2_kernel(
    const float* __restrict__ hpart,
    const float* __restrict__ rb1, const float* __restrict__ rw2, const float* __restrict__ rb2,
    const float* __restrict__ cb1, const float* __restrict__ cw2, const float* __restrict__ cb2,
    float* __restrict__ out)
{
    const int n = blockIdx.x, task = blockIdx.y;
    const int tid = threadIdx.x;
    const int b = tid >> 4, jg = tid & 15;
    const float* b1 = (task ? cb1 : rb1) + n * 128 + jg * 8;
    const float* W2 = (task ? cw2 : rw2) + n * 128 + jg * 8;
    float s = 0.f;
#pragma unroll
    for (int k = 0; k < 8; ++k) {
        float h = b1[k];
#pragma unroll
        for (int ksl = 0; ksl < 8; ++ksl)
            h += hpart[(((size_t)(ksl * 2 + task) * 64 + n) * 16 + b) * 128 + jg * 8 + k];
        s = fmaf(fmaxf(h, 0.f), W2[k], s);
    }
#pragma unroll
    for (int off = 1; off < 16; off <<= 1) s += __shfl_xor(s, off, 16);
    if (jg == 0) {
        s += (task ? cb2 : rb2)[n];
        float r = task ? (1.f / (1.f + __expf(-s)))
                       : (fmaxf(s, 0.f) + log1pf(__expf(-fabsf(s))));
        out[task * 1024 + b * 64 + n] = r;
    }
}

// ---------- launch ----------
extern "C" void kernel_launch(void* const* d_in, const int* in_sizes, int n_in,
                              void* d_out, int out_size, void* d_ws, size_t ws_size,
                              hipStream_t stream)
{
    const float* x      = (const float*)d_in[0];
    const float* wq     = (const float*)d_in[1];
    const float* bq     = (const float*)d_in[2];
    const float* wk     = (const float*)d_in[3];
    const float* bk     = (const float*)d_in[4];
    const float* wv     = (const float*)d_in[5];
    const float* bv     = (const float*)d_in[6];
    const float* wo     = (const float*)d_in[7];
    const float* bo     = (const float*)d_in[8];
    const float* emb    = (const float*)d_in[9];
    const float* rg_w1  = (const float*)d_in[10];
    const float* rg_b1  = (const float*)d_in[11];
    const float* rg_w2  = (const float*)d_in[12];
    const float* rg_b2  = (const float*)d_in[13];
    const float* reg_w1 = (const float*)d_in[14];
    const float* reg_b1 = (const float*)d_in[15];
    const float* reg_w2 = (const float*)d_in[16];
    const float* reg_b2 = (const float*)d_in[17];
    const float* cls_w1 = (const float*)d_in[18];
    const float* cls_b1 = (const float*)d_in[19];
    const float* cls_w2 = (const float*)d_in[20];
    const float* cls_b2 = (const float*)d_in[21];

    char* ws = (char*)d_ws;
    size_t off = 0;
    auto alloc = [&](size_t bytes) { size_t cur = off; off += (bytes + 255) & ~(size_t)255; return cur; };

    ushort_t* xb  = (ushort_t*)(ws + alloc((size_t)16777216 * 2));
    ushort_t* wqT = (ushort_t*)(ws + alloc((size_t)1048576 * 2));
    ushort_t* wkT = (ushort_t*)(ws + alloc((size_t)1048576 * 2));
    ushort_t* Qb  = (ushort_t*)(ws + alloc((size_t)16777216 * 2));
    ushort_t* Kb  = (ushort_t*)(ws + alloc((size_t)16777216 * 2));
    size_t zero_beg = off;
    float* wcol = (float*)(ws + alloc((size_t)131072 * 4));
    float* u    = (float*)(ws + alloc((size_t)131072 * 4));
    float* cm   = (float*)(ws + alloc((size_t)16384 * 4));
    float* gbuf = (float*)(ws + alloc((size_t)16384 * 4));
    float* Ge   = (float*)(ws + alloc((size_t)16384 * 4));
    float* Ee   = (float*)(ws + alloc((size_t)65536 * 4));
    size_t zero_end = off;
    float* DR    = (float*)(ws + alloc((size_t)1048576 * 4));
    float* hpart = (float*)(ws + alloc((size_t)2097152 * 4));

    hipMemsetAsync(ws + zero_beg, 0, zero_end - zero_beg, stream);

    prep_kernel<<<8192, 256, 0, stream>>>(x, xb);
    transpose_kernel<<<dim3(16, 16, 2), 256, 0, stream>>>(wq, wk, wqT, wkT);
    gemm_qk_kernel<<<dim3(128, 8, 2), 256, 0, stream>>>(xb, wqT, wkT, bq, bk, Qb, Kb);
    attn_mfma_kernel<<<dim3(128, 8), 256, 0, stream>>>(Qb, Kb, wcol);
    u_kernel<<<dim3(16, 16), 256, 0, stream>>>(xb, wcol, u);
    sgemm_kernel<<<dim3(4, 2, 8), 256, 0, stream>>>(u, 8192, 1024, wv, 1024, 128, bv, 128,
                                                    cm, 1024, 128, 16, 128, 1024, 1.f / 1024.f, 4);
    sgemm_kernel<<<dim3(8, 16, 1), 256, 0, stream>>>(cm, 1024, 0, wo, 1024, 0, bo, 0,
                                                     gbuf, 1024, 0, 16, 1024, 1024, 1.f, 8);
    sgemm_kernel<<<dim3(8, 16, 1), 256, 0, stream>>>(gbuf, 1024, 0, rg_w1, 1024, 0, nullptr, 0,
                                                     Ge, 1024, 0, 16, 1024, 1024, 1.f, 8);
    sgemm_kernel<<<dim3(8, 16, 1), 256, 0, stream>>>(emb, 1024, 0, rg_w1 + (size_t)1048576, 1024, 0, nullptr, 0,
                                                     Ee, 1024, 0, 64, 1024, 1024, 1.f, 8);
    gate_kernel<<<1024, 256, 0, stream>>>(Ge, Ee, rg_b1, rg_w2, rg_b2, emb, DR);
    heads_p1_kernel<<<dim3(64, 2, 8), 256, 0, stream>>>(gbuf, DR, reg_w1, cls_w1, hpart);
    heads_p2_kernel<<<dim3(64, 2), 256, 0, stream>>>(hpart, reg_b1, reg_w2, reg_b2,
                                                     cls_b1, cls_w2, cls_b2, (float*)d_out);
    (void)in_sizes; (void)n_in; (void)out_size; (void)ws_size;
}